// Round 1
// baseline (339.919 us; speedup 1.0000x reference)
//
#include <hip/hip_runtime.h>

#define B_  32
#define T_  256
#define F_  64
#define C_  16
#define CO_ 16
#define P_  64
#define S_  32
#define K_  4
#define FC_ 1024   // F*C
#define OUTC 96

// ---------------------------------------------------------------------------
// Kernel A: point_out[b,t,p] = b_p[p] + [x_flat | static] . W_p[:,p]
// M=8192 rows (b,t), K=1056, N=64. 512 blocks, 16 rows/block, 4 rows/wave.
// x row loads are wave-uniform (single 16B L1 request); W_p loads coalesced.
// ---------------------------------------------------------------------------
__global__ __launch_bounds__(256) void point_gemm(
    const float* __restrict__ x, const float* __restrict__ stat,
    const float* __restrict__ Wp, const float* __restrict__ bp,
    float* __restrict__ pout)
{
    int tid = threadIdx.x;
    int tx  = tid & 63;          // output column p
    int ty  = tid >> 6;          // wave 0..3
    int blk = blockIdx.x;        // 0..511
    int b   = blk >> 4;
    int t0  = (blk & 15) << 4;   // 16 rows per block
    int row0 = t0 + ty * 4;      // 4 rows per wave

    // static + bias contribution (identical for all rows of this b)
    float sacc = bp[tx];
    const float* wst = Wp + (size_t)FC_ * P_;
    #pragma unroll 8
    for (int s = 0; s < S_; ++s)
        sacc += stat[b * S_ + s] * wst[s * P_ + tx];

    float acc0 = sacc, acc1 = sacc, acc2 = sacc, acc3 = sacc;
    const float* xrow = x + ((size_t)(b * T_ + row0)) * FC_;
    for (int k0 = 0; k0 < FC_; k0 += 4) {
        float b0 = Wp[(size_t)(k0 + 0) * P_ + tx];
        float b1 = Wp[(size_t)(k0 + 1) * P_ + tx];
        float b2 = Wp[(size_t)(k0 + 2) * P_ + tx];
        float b3 = Wp[(size_t)(k0 + 3) * P_ + tx];
        float4 x0 = *(const float4*)(xrow + 0 * FC_ + k0);
        float4 x1 = *(const float4*)(xrow + 1 * FC_ + k0);
        float4 x2 = *(const float4*)(xrow + 2 * FC_ + k0);
        float4 x3 = *(const float4*)(xrow + 3 * FC_ + k0);
        acc0 += x0.x * b0 + x0.y * b1 + x0.z * b2 + x0.w * b3;
        acc1 += x1.x * b0 + x1.y * b1 + x1.z * b2 + x1.w * b3;
        acc2 += x2.x * b0 + x2.y * b1 + x2.z * b2 + x2.w * b3;
        acc3 += x3.x * b0 + x3.y * b1 + x3.z * b2 + x3.w * b3;
    }
    float* orow = pout + ((size_t)(b * T_ + row0)) * P_ + tx;
    orow[0 * P_] = acc0;
    orow[1 * P_] = acc1;
    orow[2 * P_] = acc2;
    orow[3 * P_] = acc3;
}

// ---------------------------------------------------------------------------
// Kernel B: grouped dilated causal conv + concat fusion + ReLU.
// Block = (b, 32-wide t tile, 16-wide f tile); thread owns one (f_loc, co)
// pair with its 64 conv weights in registers. x slices staged in LDS once.
// ---------------------------------------------------------------------------
__global__ __launch_bounds__(256) void fuse_conv(
    const float* __restrict__ x, const float* __restrict__ cw,
    const float* __restrict__ cb, const float* __restrict__ pnt,
    float* __restrict__ out)
{
    __shared__ __align__(16) float xs[38 * 256];  // 38 time slices x (16 f x 16 c)
    int tid = threadIdx.x;
    int blk = blockIdx.x;        // 0..1023
    int b   = blk >> 5;
    int r   = blk & 31;
    int t0  = (r >> 2) * 32;
    int f0  = (r & 3) * 16;
    int f_loc = tid >> 4;        // 0..15
    int co    = tid & 15;
    int f     = f0 + f_loc;

    // ---- stage x[t0-6 .. t0+31, f0..f0+15, :] into LDS (zero left pad) ----
    for (int it = 0; it < 10; ++it) {
        int v = it * 256 + tid;            // float4 index, 2432 total
        if (v < 38 * 64) {
            int slice = v >> 6;
            int pos   = v & 63;
            int tg    = t0 - 6 + slice;
            float4 val = make_float4(0.f, 0.f, 0.f, 0.f);
            if (tg >= 0)
                val = *(const float4*)(x + ((size_t)(b * T_ + tg) * F_ + f0) * C_ + pos * 4);
            *(float4*)(xs + slice * 256 + pos * 4) = val;
        }
    }

    // ---- conv weights for (f, co): 64 floats into registers ----
    float w[64];
    const float4* wg = (const float4*)(cw + ((size_t)(f * CO_ + co)) * (C_ * K_));
    #pragma unroll
    for (int j = 0; j < 16; ++j) {
        float4 v = wg[j];
        w[j * 4 + 0] = v.x; w[j * 4 + 1] = v.y;
        w[j * 4 + 2] = v.z; w[j * 4 + 3] = v.w;
    }
    float bias = cb[f * CO_ + co];

    __syncthreads();

    int lane = tid & 63;
    int g0   = tid >> 6;

    for (int tl = 0; tl < 32; ++tl) {
        int t = t0 + tl;
        // temp[b,t,f,co] = bias + sum_{c,k} x[b, t-6+2k, f, c] * w[c*4+k]
        float temp = bias;
        #pragma unroll
        for (int k = 0; k < K_; ++k) {
            const float* sp = xs + (tl + 2 * k) * 256 + f_loc * 16;
            #pragma unroll
            for (int c4 = 0; c4 < 4; ++c4) {
                float4 xv = *(const float4*)(sp + c4 * 4);
                temp += xv.x * w[(c4 * 4 + 0) * 4 + k];
                temp += xv.y * w[(c4 * 4 + 1) * 4 + k];
                temp += xv.z * w[(c4 * 4 + 2) * 4 + k];
                temp += xv.w * w[(c4 * 4 + 3) * 4 + k];
            }
        }
        float* ob = out + ((size_t)(b * T_ + t) * F_ + f0) * OUTC;
        // channels [16,32): conv result
        ob[f_loc * OUTC + 16 + co] = fmaxf(temp, 0.f);
        // channels [0,16): x passthrough
        ob[f_loc * OUTC + co] = fmaxf(xs[(tl + 6) * 256 + f_loc * 16 + co], 0.f);
        // channels [32,96): broadcast pointwise branch
        float pv = fmaxf(pnt[((size_t)(b * T_ + t)) * P_ + lane], 0.f);
        #pragma unroll
        for (int g = 0; g < 4; ++g) {
            int fl = g * 4 + g0;
            ob[fl * OUTC + 32 + lane] = pv;
        }
    }
}

extern "C" void kernel_launch(void* const* d_in, const int* in_sizes, int n_in,
                              void* d_out, int out_size, void* d_ws, size_t ws_size,
                              hipStream_t stream) {
    const float* x    = (const float*)d_in[0];
    const float* stat = (const float*)d_in[1];
    const float* cw   = (const float*)d_in[2];
    const float* cb   = (const float*)d_in[3];
    const float* Wp   = (const float*)d_in[4];
    const float* bp   = (const float*)d_in[5];
    float* out = (float*)d_out;
    float* pnt = (float*)d_ws;   // B*T*P floats = 2 MB scratch

    point_gemm<<<512, 256, 0, stream>>>(x, stat, Wp, bp, pnt);
    fuse_conv<<<1024, 256, 0, stream>>>(x, cw, cb, pnt, out);
}